// Round 5
// baseline (1306.103 us; speedup 1.0000x reference)
//
#include <hip/hip_runtime.h>
#include <math.h>

// Problem dims (fixed by reference): T=512 -> rows=511, V=32000, E=H=512.
#define ROWS 511
#define VV   32000
#define HH   512

// Scan constants
#define SLOTF   3584    // fast-path W-block size cap in floats (14336 B)
#define NLW     14      // 1KB chunks per W slot
#define DARRCAP 26112   // LDS delta-history capacity (104448 B)
#define TBL     520     // table size (covers t+4 <= 514)
#define MAXQ    17      // float4 pairs per row in register bank (covers cip <= 68)
#define AHEAD   8       // warmer lookahead in steps (~120 KB L2 window)

// Pad to multiple of 4 that is NOT a multiple of 8 (W row stride in floats).
__device__ __forceinline__ int pad4not8(int x) {
    int p = (x + 3) & ~3;
    if ((p & 7) == 0) p += 4;
    return p;
}
__device__ __forceinline__ int pad4(int x) { return (x + 3) & ~3; }

__device__ __forceinline__ int rfl(int x) { return __builtin_amdgcn_readfirstlane(x); }

// Issue N clustered float4 loads (1KB apart per k) into statically-indexed
// registers. Plain C loads: the compiler tracks vmcnt and keeps the dest regs
// live, so (unlike round-4's raw asm loads) nothing is clobbered in flight.
template<int N>
__device__ __forceinline__ void warm_issue(const float* g, float4* v) {
#pragma unroll
    for (int k = 0; k < N; ++k) v[k] = *(const float4*)(g + k * 256);
}

// ---------------- fp32 tiled GEMM:  C[m,n] (+)= sum_k A[m,k]*B[n,k] ----------------
__global__ __launch_bounds__(256) void gemm_nt(
    const float* __restrict__ A, const float* __restrict__ B, float* __restrict__ C,
    int M, int lda, int ldb, int ldc, int kChunk, int useAtomic)
{
    __shared__ float As[16][68];   // k-major, padded
    __shared__ float Bs[16][68];
    const int tid = threadIdx.x;
    const int bn = blockIdx.x, bm = blockIdx.y, bz = blockIdx.z;
    const int row = tid >> 2;            // 0..63
    const int seg = (tid & 3) << 2;      // k sub-offset {0,4,8,12}
    const int tm  = (tid >> 4) << 2;     // 0,4,..,60
    const int tn  = (tid & 15) << 2;
    const int am = bm*64 + row;
    const size_t k0 = (size_t)bz * kChunk;
    const float* Ap = A + (size_t)am*lda + k0 + seg;
    const float* Bp = B + (size_t)(bn*64 + row)*ldb + k0 + seg;
    const bool aok = (am < M);
    float acc[4][4];
#pragma unroll
    for (int i=0;i<4;i++)
#pragma unroll
        for (int j=0;j<4;j++) acc[i][j]=0.f;

    for (int kt = 0; kt < kChunk; kt += 16) {
        float4 av = aok ? *(const float4*)(Ap + kt) : make_float4(0.f,0.f,0.f,0.f);
        float4 bv = *(const float4*)(Bp + kt);       // N is always a multiple of 64
        __syncthreads();
        As[seg+0][row]=av.x; As[seg+1][row]=av.y; As[seg+2][row]=av.z; As[seg+3][row]=av.w;
        Bs[seg+0][row]=bv.x; Bs[seg+1][row]=bv.y; Bs[seg+2][row]=bv.z; Bs[seg+3][row]=bv.w;
        __syncthreads();
#pragma unroll
        for (int k=0;k<16;k++){
            const float4 a  = *(const float4*)&As[k][tm];
            const float4 b4 = *(const float4*)&Bs[k][tn];
            float ar[4]={a.x,a.y,a.z,a.w};
            float br[4]={b4.x,b4.y,b4.z,b4.w};
#pragma unroll
            for (int i=0;i<4;i++)
#pragma unroll
                for (int j=0;j<4;j++)
                    acc[i][j] += ar[i]*br[j];
        }
    }
#pragma unroll
    for (int i=0;i<4;i++){
        int gm = bm*64 + tm + i;
        if (gm < M) {
            float* Cp = C + (size_t)gm*ldc + bn*64 + tn;
            if (useAtomic) {
                atomicAdd(Cp+0, acc[i][0]); atomicAdd(Cp+1, acc[i][1]);
                atomicAdd(Cp+2, acc[i][2]); atomicAdd(Cp+3, acc[i][3]);
            } else {
                *(float4*)Cp = make_float4(acc[i][0],acc[i][1],acc[i][2],acc[i][3]);
            }
        }
    }
}

// ---------------- R[j] = sum_i |W_h[j,i]| ----------------
__global__ __launch_bounds__(64) void rsum_kernel(const float* __restrict__ W_h, float* __restrict__ R)
{
    const int j = blockIdx.x;
    const int lane = threadIdx.x;
    float s = 0.f;
    for (int i = lane; i < HH; i += 64) s += fabsf(W_h[(size_t)j*HH + i]);
#pragma unroll
    for (int off = 32; off >= 1; off >>= 1) s += __shfl_down(s, off);
    if (lane == 0) R[j] = s;
}

// ---------------- classify: xp += b; S = step(xp); uncertain index lists ----------------
__global__ __launch_bounds__(512) void classify_kernel(
    float* __restrict__ xp, const float* __restrict__ b, const float* __restrict__ R,
    float* __restrict__ Hm, int* __restrict__ idxJ, int* __restrict__ cnt)
{
    const int t = blockIdx.x;       // 0..510
    const int j = threadIdx.x;      // 0..511
    __shared__ int c;
    if (j == 0) c = 0;
    __syncthreads();
    float v = xp[(size_t)t*HH + j] + b[j];
    xp[(size_t)t*HH + j] = v;
    Hm[(size_t)t*HH + j] = (v > 0.f) ? 1.f : 0.f;
    if (fabsf(v) < R[j] + 30.0f) {       // recurrent term bound: |W_h@h| <= R[j]
        int slot = atomicAdd(&c, 1);
        if (slot < 128) idxJ[t*128 + slot] = j;
    }
    __syncthreads();
    if (j == 0) cnt[t] = (c < 128) ? c : 128;
}

// ---------------- parallel prefixes: wsub block offsets + delta-history offsets ----------------
__global__ __launch_bounds__(512) void prefix_kernel(
    const int* __restrict__ cnt, int* __restrict__ offs, int* __restrict__ d4offs)
{
    __shared__ int sA[512];
    __shared__ int sB[512];
    const int t = threadIdx.x;
    int a = 0, b = 0;
    if (t >= 1 && t <= 510) a = cnt[t] * pad4not8(cnt[t-1]);   // cj * ci_pad
    if (t <= 510) b = pad4(cnt[t]);
    sA[t] = a; sB[t] = b;
    int va = a, vb = b;
    __syncthreads();
    for (int d = 1; d < 512; d <<= 1) {
        int ua = (t >= d) ? sA[t-d] : 0;
        int ub = (t >= d) ? sB[t-d] : 0;
        __syncthreads();
        va += ua; vb += ub;
        sA[t] = va; sB[t] = vb;
        __syncthreads();
    }
    if (t <= 510) offs[t] = va - a;     // exclusive prefix (multiple of 4)
    d4offs[t] = vb - b;                 // t=511 slot -> padded total
}

// ---------------- gather: pack W_h submatrix j-major + {zbase, step} pairs ----------------
__global__ __launch_bounds__(256) void gather_kernel(
    const float* __restrict__ W_h, const float* __restrict__ xp, const float* __restrict__ U,
    const int* __restrict__ idxJ, const int* __restrict__ cnt, const int* __restrict__ offs,
    float* __restrict__ wsub, int wsub_cap, float2* __restrict__ zs)
{
    const int t = blockIdx.x;       // 0..510
    const int cj = cnt[t];
    for (int jj = threadIdx.x; jj < cj; jj += 256) {
        int j = idxJ[t*128 + jj];
        float xpv = xp[(size_t)t*HH + j];
        float v = xpv;
        if (t > 0) v += U[(size_t)(t-1)*HH + j];
        zs[t*128 + jj] = make_float2(v, (xpv > 0.f) ? 1.f : 0.f);
    }
    if (t == 0) return;
    const int ci  = cnt[t-1];
    const int cip = pad4not8(ci);
    const int nw  = cj * cip;
    const int base = offs[t];
    if (base + nw > wsub_cap) return;    // scan falls back to direct W_h gather
    for (int r = 0; r < cj; ++r) {
        const float* Wrow = W_h + (size_t)idxJ[t*128 + r] * HH;
        for (int c = threadIdx.x; c < cip; c += 256)
            wsub[base + r*cip + c] = (c < ci) ? Wrow[idxJ[(t-1)*128 + c]] : 0.f;
    }
}

// ---------------- sequential scan: 1 compute wave + 3 L2-warmer waves ----------------
// Round-4 post-mortem: the asm warm loads crashed the kernel — the asm dest VGPR
// was dead immediately, the allocator reused it while the load was in flight, and
// the late-returning load clobbered live registers (and waves returned with loads
// outstanding). Round 5 keeps the warming THEORY but uses compiler-tracked plain
// C float4 loads: warm_issue<N> fills statically-indexed register arrays (no
// scratch), results fold into a dummy accumulator stored to an LDS sink (cannot
// be DCE'd, no global side effects). Each warmer owns a fixed compile-time chunk
// range of each step's W slot (wwid 0: 0-4, 1: 5-9, 2: 10-13 + zs) and batches
// 3 steps (15KB in flight) per waitcnt -> one HBM latency per 3 steps per warmer.
// Pacing: LDS prog counter, AHEAD-step window (~120KB << 4MB L2).
// Consumer = round-2 two-bank form (unchanged); its wsub/zs loads should now hit
// this XCD's L2 (~250cy) instead of HBM (~900-1200cy).
__global__ __launch_bounds__(256, 1) void scan_kernel(
    const float2* __restrict__ zs, const int* __restrict__ idxJ,
    const int* __restrict__ cnt, const int* __restrict__ offs, const int* __restrict__ d4offs,
    const float* __restrict__ wsub, int wsub_cap,
    const float* __restrict__ W_h, float* __restrict__ Hm, float* __restrict__ darrg)
{
    __shared__ __align__(16) float  darr[DARRCAP];        // 104448 B
    __shared__ __align__(16) float  db[2][132];           // overflow-mode ping-pong
    __shared__ __align__(16) int4   rec[TBL];             //   8320 B {cnt, offs, d4offs, 0}
    __shared__ int   prog;                                // consumer progress (step #)
    __shared__ float wsink[4];                            // warmer DCE sink
    const int tid  = threadIdx.x;
    const int wid  = tid >> 6;
    const int lane = tid & 63;
    const float* zsf = (const float*)zs;

    for (int i = tid; i < TBL; i += 256) {
        int c = (i < ROWS) ? cnt[i]    : 0;
        int o = (i < ROWS) ? offs[i]   : 0;
        int d = (i < ROWS) ? d4offs[i] : d4offs[511];
        rec[i] = make_int4(c, o, d, 0);
    }
    for (int i = tid * 4; i < DARRCAP; i += 1024)
        *(float4*)&darr[i] = make_float4(0.f, 0.f, 0.f, 0.f);
    for (int i = tid; i < 132; i += 256) { db[0][i] = 0.f; db[1][i] = 0.f; }
    if (tid == 0) prog = 0;
    __syncthreads();

    const int  total   = rfl(rec[511].z);
    const bool useDarr = (total <= DARRCAP - 64);

    if (wid != 0) {
        // ---------------- warmer waves (wid 1..3) ----------------
        const int wwid = wid - 1;          // 0..2
        float acc = 0.f;
        for (int s0 = 1; s0 <= 508; s0 += 3) {   // batches cover steps 1..510
            while (*(volatile int*)&prog + AHEAD < s0 + 2)
                __builtin_amdgcn_s_sleep(8);
            int wb0 = rec[s0    ].y; int sb0 = (wb0 + SLOTF <= wsub_cap) ? wb0 : 0;
            int wb1 = rec[s0 + 1].y; int sb1 = (wb1 + SLOTF <= wsub_cap) ? wb1 : 0;
            int wb2 = rec[s0 + 2].y; int sb2 = (wb2 + SLOTF <= wsub_cap) ? wb2 : 0;
            const float* g0 = wsub + sb0 + lane * 4;
            const float* g1 = wsub + sb1 + lane * 4;
            const float* g2 = wsub + sb2 + lane * 4;
            float4 v0[5], v1[5], v2[5];
            if (wwid == 0) {
                warm_issue<5>(g0, v0);
                warm_issue<5>(g1, v1);
                warm_issue<5>(g2, v2);
            } else if (wwid == 1) {
                warm_issue<5>(g0 + 5 * 256, v0);
                warm_issue<5>(g1 + 5 * 256, v1);
                warm_issue<5>(g2 + 5 * 256, v2);
            } else {
                warm_issue<4>(g0 + 10 * 256, v0);
                warm_issue<4>(g1 + 10 * 256, v1);
                warm_issue<4>(g2 + 10 * 256, v2);
                v0[4] = *(const float4*)(zsf + (size_t)(s0    ) * 256 + lane * 4);
                v1[4] = *(const float4*)(zsf + (size_t)(s0 + 1) * 256 + lane * 4);
                v2[4] = *(const float4*)(zsf + (size_t)(s0 + 2) * 256 + lane * 4);
            }
#pragma unroll
            for (int k = 0; k < 5; ++k)
                acc += (v0[k].x + v0[k].y + v0[k].z + v0[k].w)
                     + (v1[k].x + v1[k].y + v1[k].z + v1[k].w)
                     + (v2[k].x + v2[k].y + v2[k].z + v2[k].w);
        }
        if (lane == 0) wsink[wwid] = acc;   // keep the loads alive; LDS-only effect
        return;
    }

    // ---------------- consumer wave (wid 0) ----------------
    // ---- t = 0: h = sigmoid(zbase), delta = h - step ----
    {
        const int cj0 = rfl(rec[0].x);
        for (int jj = lane; jj < cj0; jj += 64) {
            float2 zz = zs[jj];
            float h = 1.f / (1.f + __expf(-zz.x));
            float d = h - zz.y;
            if (useDarr) darr[jj] = d;
            else { db[0][jj] = d; Hm[idxJ[jj]] = h; }
        }
    }

    // ---- register W banks + prefetched z, ping-pong ----
    float4 WA[MAXQ], WB[MAXQ];
    float2 zA, zB;

    // carried wave-uniform bookkeeping
    int ciP, sd4P;              // step t-1: cnt, d-offset
    int cjC, sd4C, n4C;         // step t:   cnt, d-offset, cip>>2
    bool fastC;
    int cjN, wbN, sd4N;         // step t+1: cnt, wsub base, d-offset
    int n4N; bool fastN;
    int4 rnNN;                  // rec[t+2]

    // Issue prefetch of W(step TT1) into bank NXTW and z(step TT1) into ZN.
    // Uses: cjC (= cnt[TT1-1] -> cip), cjN/wbN (= cnt/offs of TT1).
#define PREFETCH(TT1, NXTW, ZN) do {                                            \
        int cipN_ = pad4not8(cjC);                                              \
        n4N = cipN_ >> 2;                                                       \
        fastN = (cjN <= 64) && (cipN_ <= 68) &&                                 \
                ((long)cjN * cipN_ <= SLOTF) && (wbN + SLOTF <= wsub_cap);      \
        int rowN_ = min(lane, max(cjN - 1, 0));                                 \
        const float* gW_ = wsub + (fastN ? (wbN + rowN_ * cipN_) : 0);          \
        _Pragma("unroll")                                                       \
        for (int q = 0; q < MAXQ; ++q) {                                        \
            int off_ = (q < n4N) ? (q << 2) : 0;                                \
            NXTW[q] = *(const float4*)(gW_ + off_);                             \
        }                                                                       \
        ZN = *(const float2*)&zsf[(size_t)(TT1) * 256 + (lane << 1)];           \
    } while (0)

#define COMPUTE(TT, CURW, ZC) do {                                              \
        const float* dvec_ = useDarr ? &darr[sd4P] : db[((TT) - 1) & 1];        \
        if (fastC) {                                                            \
            if (lane < cjC) {                                                   \
                const float4* dr_ = (const float4*)dvec_;                       \
                float4 Dv[MAXQ];                                                \
                _Pragma("unroll")                                               \
                for (int g = 0; g < MAXQ; g += 4) {                             \
                    if (g < n4C) {                                              \
                        _Pragma("unroll")                                       \
                        for (int q = g; q < g + 4 && q < MAXQ; ++q)             \
                            Dv[q] = dr_[q];                                     \
                    }                                                           \
                }                                                               \
                float a0 = 0.f, a1 = 0.f, a2 = 0.f, a3 = 0.f;                   \
                _Pragma("unroll")                                               \
                for (int q = 0; q < MAXQ; ++q) {                                \
                    if (q < n4C) {                                              \
                        a0 += CURW[q].x * Dv[q].x; a1 += CURW[q].y * Dv[q].y;   \
                        a2 += CURW[q].z * Dv[q].z; a3 += CURW[q].w * Dv[q].w;   \
                    }                                                           \
                }                                                               \
                float z = ZC.x + (a0 + a1) + (a2 + a3);                         \
                float h = 1.f / (1.f + __expf(-z));                             \
                float d = h - ZC.y;                                             \
                if (useDarr) darr[sd4C + lane] = d;                             \
                else { db[(TT) & 1][lane] = d;                                  \
                       Hm[(size_t)(TT)*HH + idxJ[(TT)*128 + lane]] = h; }       \
            }                                                                   \
        } else {                                                                \
            for (int jj = lane; jj < cjC; jj += 64) {                           \
                int j = idxJ[(TT)*128 + jj];                                    \
                float2 zz = zs[(size_t)(TT)*128 + jj];                          \
                float zv = zz.x;                                                \
                for (int ii = 0; ii < ciP; ++ii)                                \
                    zv += W_h[(size_t)j*HH + idxJ[((TT)-1)*128 + ii]] * dvec_[ii]; \
                float h = 1.f / (1.f + __expf(-zv));                            \
                float dd = h - zz.y;                                            \
                if (useDarr) darr[sd4C + jj] = dd;                              \
                else { db[(TT) & 1][jj] = dd;                                   \
                       Hm[(size_t)(TT)*HH + j] = h; }                           \
            }                                                                   \
        }                                                                       \
        if (lane == 0) *(volatile int*)&prog = (TT);                            \
    } while (0)

#define ROTATE(RN3) do {                                                        \
        ciP = cjC; sd4P = sd4C;                                                 \
        cjC = cjN; sd4C = sd4N; fastC = fastN; n4C = n4N;                       \
        cjN = rfl(rnNN.x); wbN = rfl(rnNN.y); sd4N = rfl(rnNN.z);               \
        rnNN = (RN3);                                                           \
    } while (0)

    // ---- prime the pipeline for step 1 ----
    ciP  = rfl(rec[0].x);
    sd4P = rfl(rec[0].z);
    cjC  = ciP;                    // so PREFETCH computes cip for step 1 from cnt[0]
    cjN  = rfl(rec[1].x);
    wbN  = rfl(rec[1].y);
    sd4N = rfl(rec[1].z);
    PREFETCH(1, WA, zA);
    // rotate into step-1 state
    cjC = cjN; sd4C = sd4N; fastC = fastN; n4C = n4N;
    cjN = rfl(rec[2].x); wbN = rfl(rec[2].y); sd4N = rfl(rec[2].z);
    rnNN = rec[3];

    for (int t = 1; t <= 510; t += 2) {
        {
            PREFETCH(t + 1, WB, zB);
            int4 rn3 = rec[t + 3];
            COMPUTE(t, WA, zA);
            ROTATE(rn3);
        }
        {
            PREFETCH(t + 2, WA, zA);
            int4 rn3 = rec[t + 4];
            COMPUTE(t + 1, WB, zB);
            ROTATE(rn3);
        }
    }

    // dump delta history for the parallel scatter kernel
    if (useDarr) {
        for (int i = lane * 4; i < total; i += 256)
            *(float4*)&darrg[i] = *(float4*)&darr[i];
    }
#undef PREFETCH
#undef COMPUTE
#undef ROTATE
}

// ---------------- parallel scatter: Hm[t, idxJ] = step + delta ----------------
__global__ __launch_bounds__(64) void scatter_kernel(
    const float2* __restrict__ zs, const int* __restrict__ idxJ,
    const int* __restrict__ cnt, const int* __restrict__ d4offs,
    const float* __restrict__ darrg, float* __restrict__ Hm)
{
    if (d4offs[511] > DARRCAP - 64) return;   // overflow mode: scan wrote Hm directly
    const int t = blockIdx.x;
    const int c = cnt[t];
    for (int jj = threadIdx.x; jj < c; jj += 64)
        Hm[(size_t)t*HH + idxJ[t*128 + jj]] = zs[(size_t)t*128 + jj].y + darrg[d4offs[t] + jj];
}

// ---------------- row softmax over V=32000, in place on d_out ----------------
__global__ __launch_bounds__(256) void softmax_kernel(float* __restrict__ out)
{
    const int row = blockIdx.x;
    const int tid = threadIdx.x;
    float* p = out + (size_t)row * VV;
    float m = -INFINITY, l = 0.f;
    for (int i = tid; i < VV; i += 256) {          // 125 iters exactly
        float x = p[i];
        if (x > m) { l = l * __expf(m - x) + 1.f; m = x; }
        else       { l += __expf(x - m); }
    }
#pragma unroll
    for (int off = 32; off >= 1; off >>= 1) {
        float m2 = __shfl_down(m, off);
        float l2 = __shfl_down(l, off);
        float M  = fmaxf(m, m2);
        l = l * __expf(m - M) + l2 * __expf(m2 - M);
        m = M;
    }
    __shared__ float sm[4], sl[4];
    const int wid = tid >> 6, lane = tid & 63;
    if (lane == 0) { sm[wid] = m; sl[wid] = l; }
    __syncthreads();
    if (tid == 0) {
        float M = sm[0], L = sl[0];
        for (int w = 1; w < 4; ++w) {
            float M2 = fmaxf(M, sm[w]);
            L = L * __expf(M - M2) + sl[w] * __expf(sm[w] - M2);
            M = M2;
        }
        sm[0] = M; sl[0] = 1.0f / L;
    }
    __syncthreads();
    const float M = sm[0], inv = sl[0];
    for (int i = tid; i < VV; i += 256) p[i] = __expf(p[i] - M) * inv;
}

// ---------------- launcher ----------------
extern "C" void kernel_launch(void* const* d_in, const int* in_sizes, int n_in,
                              void* d_out, int out_size, void* d_ws, size_t ws_size,
                              hipStream_t stream)
{
    const float* sent = (const float*)d_in[0];
    const float* W_e  = (const float*)d_in[1];
    const float* W_x  = (const float*)d_in[2];
    const float* W_h  = (const float*)d_in[3];
    const float* W_p  = (const float*)d_in[4];
    const float* b    = (const float*)d_in[5];
    float* out = (float*)d_out;
    float* ws  = (float*)d_ws;

    // workspace layout (float offsets)
    float*  emb    = ws;                      // 262144
    float*  xp     = ws + 262144;             // 262144
    float*  U      = ws + 524288;             // 262144
    float*  Hm     = ws + 786432;             // 262144
    float*  R      = ws + 1048576;            // 512
    int*    cnt    = (int*)(ws + 1049088);    // 512
    int*    idxJ   = (int*)(ws + 1049600);    // 511*128 -> 65536
    int*    offs   = (int*)(ws + 1115136);    // 512
    int*    d4offs = (int*)(ws + 1115648);    // 512
    float2* zs     = (float2*)(ws + 1116160); // 511*128 float2 -> 130816 floats
    float*  darrg  = ws + 1246976;            // 26112
    float*  wsub   = ws + 1273088;
    long avail = (long)(ws_size / 4) - 1273088;
    int wsub_cap = (avail > 8388608L) ? 8388608 : (avail > 0 ? (int)avail : 0);

    // zero the atomic-accumulated buffers (emb, xp, U)
    hipMemsetAsync(ws, 0, (size_t)786432 * sizeof(float), stream);

    rsum_kernel<<<512, 64, 0, stream>>>(W_h, R);

    // emb = sent[:511] @ W_e^T   (K=32000, split-K 8)
    gemm_nt<<<dim3(8, 8, 8), 256, 0, stream>>>(sent, W_e, emb, ROWS, VV, VV, HH, 4000, 1);
    // xp_raw = emb @ W_x^T       (K=512, split-K 4)
    gemm_nt<<<dim3(8, 8, 4), 256, 0, stream>>>(emb, W_x, xp, ROWS, HH, HH, HH, 128, 1);

    classify_kernel<<<ROWS, 512, 0, stream>>>(xp, b, R, Hm, idxJ, cnt);

    // U = S @ W_h^T  (S currently stored in Hm)
    gemm_nt<<<dim3(8, 8, 4), 256, 0, stream>>>(Hm, W_h, U, ROWS, HH, HH, HH, 128, 1);

    prefix_kernel<<<1, 512, 0, stream>>>(cnt, offs, d4offs);
    gather_kernel<<<ROWS, 256, 0, stream>>>(W_h, xp, U, idxJ, cnt, offs, wsub, wsub_cap, zs);
    scan_kernel<<<1, 256, 0, stream>>>(zs, idxJ, cnt, offs, d4offs, wsub, wsub_cap, W_h, Hm, darrg);
    scatter_kernel<<<ROWS, 64, 0, stream>>>(zs, idxJ, cnt, d4offs, darrg, Hm);

    // logits = H @ W_p^T  -> d_out
    gemm_nt<<<dim3(500, 8, 1), 256, 0, stream>>>(Hm, W_p, out, ROWS, HH, HH, VV, 512, 0);
    softmax_kernel<<<ROWS, 256, 0, stream>>>(out);
}

// Round 6
// 1224.413 us; speedup vs baseline: 1.0667x; 1.0667x over previous
//
#include <hip/hip_runtime.h>
#include <math.h>

// Problem dims (fixed by reference): T=512 -> rows=511, V=32000, E=H=512.
#define ROWS 511
#define VV   32000
#define HH   512

// Scan constants
#define SLOTF   3584    // fast-path W-block size cap in floats (14336 B)
#define DARRCAP 26112   // LDS delta-history capacity (104448 B)
#define TBL     520     // table size (covers t+3 <= 513)
#define MAXQ    17      // float4 pairs per row total (covers cip <= 68)
#define MAXQW   5       // float4 pairs per row PER WAVE (q = wid + 4*i, i < 5)

// Pad to multiple of 4 that is NOT a multiple of 8 (W row stride in floats).
__device__ __forceinline__ int pad4not8(int x) {
    int p = (x + 3) & ~3;
    if ((p & 7) == 0) p += 4;
    return p;
}
__device__ __forceinline__ int pad4(int x) { return (x + 3) & ~3; }

__device__ __forceinline__ int rfl(int x) { return __builtin_amdgcn_readfirstlane(x); }

// ---------------- fp32 tiled GEMM:  C[m,n] (+)= sum_k A[m,k]*B[n,k] ----------------
__global__ __launch_bounds__(256) void gemm_nt(
    const float* __restrict__ A, const float* __restrict__ B, float* __restrict__ C,
    int M, int lda, int ldb, int ldc, int kChunk, int useAtomic)
{
    __shared__ float As[16][68];   // k-major, padded
    __shared__ float Bs[16][68];
    const int tid = threadIdx.x;
    const int bn = blockIdx.x, bm = blockIdx.y, bz = blockIdx.z;
    const int row = tid >> 2;            // 0..63
    const int seg = (tid & 3) << 2;      // k sub-offset {0,4,8,12}
    const int tm  = (tid >> 4) << 2;     // 0,4,..,60
    const int tn  = (tid & 15) << 2;
    const int am = bm*64 + row;
    const size_t k0 = (size_t)bz * kChunk;
    const float* Ap = A + (size_t)am*lda + k0 + seg;
    const float* Bp = B + (size_t)(bn*64 + row)*ldb + k0 + seg;
    const bool aok = (am < M);
    float acc[4][4];
#pragma unroll
    for (int i=0;i<4;i++)
#pragma unroll
        for (int j=0;j<4;j++) acc[i][j]=0.f;

    for (int kt = 0; kt < kChunk; kt += 16) {
        float4 av = aok ? *(const float4*)(Ap + kt) : make_float4(0.f,0.f,0.f,0.f);
        float4 bv = *(const float4*)(Bp + kt);       // N is always a multiple of 64
        __syncthreads();
        As[seg+0][row]=av.x; As[seg+1][row]=av.y; As[seg+2][row]=av.z; As[seg+3][row]=av.w;
        Bs[seg+0][row]=bv.x; Bs[seg+1][row]=bv.y; Bs[seg+2][row]=bv.z; Bs[seg+3][row]=bv.w;
        __syncthreads();
#pragma unroll
        for (int k=0;k<16;k++){
            const float4 a  = *(const float4*)&As[k][tm];
            const float4 b4 = *(const float4*)&Bs[k][tn];
            float ar[4]={a.x,a.y,a.z,a.w};
            float br[4]={b4.x,b4.y,b4.z,b4.w};
#pragma unroll
            for (int i=0;i<4;i++)
#pragma unroll
                for (int j=0;j<4;j++)
                    acc[i][j] += ar[i]*br[j];
        }
    }
#pragma unroll
    for (int i=0;i<4;i++){
        int gm = bm*64 + tm + i;
        if (gm < M) {
            float* Cp = C + (size_t)gm*ldc + bn*64 + tn;
            if (useAtomic) {
                atomicAdd(Cp+0, acc[i][0]); atomicAdd(Cp+1, acc[i][1]);
                atomicAdd(Cp+2, acc[i][2]); atomicAdd(Cp+3, acc[i][3]);
            } else {
                *(float4*)Cp = make_float4(acc[i][0],acc[i][1],acc[i][2],acc[i][3]);
            }
        }
    }
}

// ---------------- R[j] = sum_i |W_h[j,i]| ----------------
__global__ __launch_bounds__(64) void rsum_kernel(const float* __restrict__ W_h, float* __restrict__ R)
{
    const int j = blockIdx.x;
    const int lane = threadIdx.x;
    float s = 0.f;
    for (int i = lane; i < HH; i += 64) s += fabsf(W_h[(size_t)j*HH + i]);
#pragma unroll
    for (int off = 32; off >= 1; off >>= 1) s += __shfl_down(s, off);
    if (lane == 0) R[j] = s;
}

// ---------------- classify: xp += b; S = step(xp); uncertain index lists ----------------
__global__ __launch_bounds__(512) void classify_kernel(
    float* __restrict__ xp, const float* __restrict__ b, const float* __restrict__ R,
    float* __restrict__ Hm, int* __restrict__ idxJ, int* __restrict__ cnt)
{
    const int t = blockIdx.x;       // 0..510
    const int j = threadIdx.x;      // 0..511
    __shared__ int c;
    if (j == 0) c = 0;
    __syncthreads();
    float v = xp[(size_t)t*HH + j] + b[j];
    xp[(size_t)t*HH + j] = v;
    Hm[(size_t)t*HH + j] = (v > 0.f) ? 1.f : 0.f;
    if (fabsf(v) < R[j] + 30.0f) {       // recurrent term bound: |W_h@h| <= R[j]
        int slot = atomicAdd(&c, 1);
        if (slot < 128) idxJ[t*128 + slot] = j;
    }
    __syncthreads();
    if (j == 0) cnt[t] = (c < 128) ? c : 128;
}

// ---------------- parallel prefixes: wsub block offsets + delta-history offsets ----------------
__global__ __launch_bounds__(512) void prefix_kernel(
    const int* __restrict__ cnt, int* __restrict__ offs, int* __restrict__ d4offs)
{
    __shared__ int sA[512];
    __shared__ int sB[512];
    const int t = threadIdx.x;
    int a = 0, b = 0;
    if (t >= 1 && t <= 510) a = cnt[t] * pad4not8(cnt[t-1]);   // cj * ci_pad
    if (t <= 510) b = pad4(cnt[t]);
    sA[t] = a; sB[t] = b;
    int va = a, vb = b;
    __syncthreads();
    for (int d = 1; d < 512; d <<= 1) {
        int ua = (t >= d) ? sA[t-d] : 0;
        int ub = (t >= d) ? sB[t-d] : 0;
        __syncthreads();
        va += ua; vb += ub;
        sA[t] = va; sB[t] = vb;
        __syncthreads();
    }
    if (t <= 510) offs[t] = va - a;     // exclusive prefix (multiple of 4)
    d4offs[t] = vb - b;                 // t=511 slot -> padded total
}

// ---------------- gather: pack W_h submatrix j-major + {zbase, step} pairs ----------------
__global__ __launch_bounds__(256) void gather_kernel(
    const float* __restrict__ W_h, const float* __restrict__ xp, const float* __restrict__ U,
    const int* __restrict__ idxJ, const int* __restrict__ cnt, const int* __restrict__ offs,
    float* __restrict__ wsub, int wsub_cap, float2* __restrict__ zs)
{
    const int t = blockIdx.x;       // 0..510
    const int cj = cnt[t];
    for (int jj = threadIdx.x; jj < cj; jj += 256) {
        int j = idxJ[t*128 + jj];
        float xpv = xp[(size_t)t*HH + j];
        float v = xpv;
        if (t > 0) v += U[(size_t)(t-1)*HH + j];
        zs[t*128 + jj] = make_float2(v, (xpv > 0.f) ? 1.f : 0.f);
    }
    if (t == 0) return;
    const int ci  = cnt[t-1];
    const int cip = pad4not8(ci);
    const int nw  = cj * cip;
    const int base = offs[t];
    if (base + nw > wsub_cap) return;    // scan falls back to direct W_h gather
    for (int r = 0; r < cj; ++r) {
        const float* Wrow = W_h + (size_t)idxJ[t*128 + r] * HH;
        for (int c = threadIdx.x; c < cip; c += 256)
            wsub[base + r*cip + c] = (c < ci) ? Wrow[idxJ[(t-1)*128 + c]] : 0.f;
    }
}

// ---------------- sequential scan: COOPERATIVE 4-WAVE, K-split dot product ----------------
// Round-5 post-mortem: same-CU L2 warming added MSHR contention (398 -> 491 us);
// falsifier fired -> pivot to cooperative compute.
// Rounds 2/3 showed the register pipeline collapses because each bank is 17
// float4 (68 VGPR). Fix: split the dot's K dimension across the block's 4 waves
// (wave w owns q = w + 4i, i<5). Per-wave bank = 5 float4 = 20 VGPR, so a
// depth-2 3-bank pipeline is only 60 VGPR/wave -> no pressure, loads stay
// hoisted, HBM/L3 latency finally hidden. Per step: each wave FMAs its quarter,
// writes one partial per lane to psum (parity double-buffered), ONE raw
// s_barrier (manual lgkmcnt(0) only -- W prefetches stay in flight across it),
// then every wave redundantly reads the 4 partials and finishes (sigmoid, delta,
// darr write). Redundant finish makes next-step dvec reads self-visible within
// each wave -> one barrier per step. Parity buffering is safe under wave skew:
// passing barrier(t+1) implies all waves completed their psum(t) reads.
// Slow path (rare): split jj over 256 threads, __syncthreads at step end.
__global__ __launch_bounds__(256, 1) void scan_kernel(
    const float2* __restrict__ zs, const int* __restrict__ idxJ,
    const int* __restrict__ cnt, const int* __restrict__ offs, const int* __restrict__ d4offs,
    const float* __restrict__ wsub, int wsub_cap,
    const float* __restrict__ W_h, float* __restrict__ Hm, float* __restrict__ darrg)
{
    __shared__ __align__(16) float  darr[DARRCAP];        // 104448 B
    __shared__ __align__(16) float  db[2][132];           // overflow-mode ping-pong
    __shared__ __align__(16) int4   rec[TBL];             //   8320 B {cnt, offs, d4offs, 0}
    __shared__ float psum[2][4][72];                      //   2304 B partial sums (parity)
    const int tid  = threadIdx.x;
    const int wid  = tid >> 6;       // 0..3
    const int lane = tid & 63;
    const float* zsf = (const float*)zs;

    for (int i = tid; i < TBL; i += 256) {
        int c = (i < ROWS) ? cnt[i]    : 0;
        int o = (i < ROWS) ? offs[i]   : 0;
        int d = (i < ROWS) ? d4offs[i] : d4offs[511];
        rec[i] = make_int4(c, o, d, 0);
    }
    for (int i = tid * 4; i < DARRCAP; i += 1024)
        *(float4*)&darr[i] = make_float4(0.f, 0.f, 0.f, 0.f);
    for (int i = tid; i < 132; i += 256) { db[0][i] = 0.f; db[1][i] = 0.f; }
    __syncthreads();

    const int  total   = rfl(rec[511].z);
    const bool useDarr = (total <= DARRCAP - 64);

    // ---- t = 0: h = sigmoid(zbase), delta = h - step ----
    {
        const int cj0 = rfl(rec[0].x);
        for (int jj = tid; jj < cj0; jj += 256) {
            float2 zz = zs[jj];
            float h = 1.f / (1.f + __expf(-zz.x));
            float d = h - zz.y;
            if (useDarr) darr[jj] = d;
            else { db[0][jj] = d; Hm[idxJ[jj]] = h; }
        }
    }
    __syncthreads();

    // ---- per-wave register W banks (5 float4 each) + prefetched z ----
    float4 W0[MAXQW], W1[MAXQW], W2[MAXQW];
    float2 z0, z1, z2;

    // carried wave-uniform bookkeeping (identical across waves)
    int ciP, sd4P;                    // step t-1: cnt, d-offset
    int cjC, sd4C, n4C; bool fastC;   // step t (current compute)
    int cjN, sd4N, n4N; bool fastN;   // step t+1
    int cj2, wb2, sd42;               // step t+2 raw rec

    // Issue prefetch of this wave's quarter of W(step TT) into BANK, z into ZB.
#define PF(CJPREV, CJT, WBT, BANK, ZB, TT, N4OUT, FASTOUT) do {                 \
        int cip_ = pad4not8(CJPREV);                                            \
        N4OUT = cip_ >> 2;                                                      \
        FASTOUT = ((CJT) <= 64) && (cip_ <= 68) &&                              \
                  ((long)(CJT) * cip_ <= SLOTF) && ((WBT) + SLOTF <= wsub_cap); \
        int row_ = min(lane, max((CJT) - 1, 0));                                \
        const float* gW_ = wsub + (FASTOUT ? ((WBT) + row_ * cip_) : 0);        \
        _Pragma("unroll")                                                       \
        for (int i = 0; i < MAXQW; ++i) {                                       \
            int q_ = wid + 4 * i;                                               \
            int off_ = (q_ < N4OUT) ? (q_ << 2) : 0;                            \
            BANK[i] = *(const float4*)(gW_ + off_);                             \
        }                                                                       \
        ZB = *(const float2*)&zsf[(size_t)(TT) * 256 + (lane << 1)];            \
    } while (0)

#define COMPUTE(TT, CURW, ZC) do {                                              \
        const float* dvec_ = useDarr ? &darr[sd4P] : db[((TT) - 1) & 1];        \
        if (fastC) {                                                            \
            const float4* dr_ = (const float4*)dvec_;                           \
            float4 Dv[MAXQW];                                                   \
            _Pragma("unroll")                                                   \
            for (int i = 0; i < MAXQW; ++i) {                                   \
                int q_ = wid + 4 * i;                                           \
                Dv[i] = dr_[(q_ < n4C) ? q_ : 0];                               \
            }                                                                   \
            float a0 = 0.f, a1 = 0.f, a2 = 0.f, a3 = 0.f;                       \
            _Pragma("unroll")                                                   \
            for (int i = 0; i < MAXQW; ++i) {                                   \
                int q_ = wid + 4 * i;                                           \
                if (q_ < n4C) {                                                 \
                    a0 += CURW[i].x * Dv[i].x; a1 += CURW[i].y * Dv[i].y;       \
                    a2 += CURW[i].z * Dv[i].z; a3 += CURW[i].w * Dv[i].w;       \
                }                                                               \
            }                                                                   \
            psum[(TT) & 1][wid][lane] = (a0 + a1) + (a2 + a3);                  \
            __asm__ __volatile__("s_waitcnt lgkmcnt(0)" ::: "memory");          \
            __builtin_amdgcn_s_barrier();                                       \
            if (lane < cjC) {                                                   \
                float p0 = psum[(TT) & 1][0][lane];                             \
                float p1 = psum[(TT) & 1][1][lane];                             \
                float p2 = psum[(TT) & 1][2][lane];                             \
                float p3 = psum[(TT) & 1][3][lane];                             \
                float z = ZC.x + ((p0 + p1) + (p2 + p3));                       \
                float h = 1.f / (1.f + __expf(-z));                             \
                float d = h - ZC.y;                                             \
                if (useDarr) darr[sd4C + lane] = d;                             \
                else { db[(TT) & 1][lane] = d;                                  \
                       if (wid == 0)                                            \
                           Hm[(size_t)(TT)*HH + idxJ[(TT)*128 + lane]] = h; }   \
            }                                                                   \
        } else {                                                                \
            for (int jj = tid; jj < cjC; jj += 256) {                           \
                int j = idxJ[(TT)*128 + jj];                                    \
                float2 zz = zs[(size_t)(TT)*128 + jj];                          \
                float zv = zz.x;                                                \
                for (int ii = 0; ii < ciP; ++ii)                                \
                    zv += W_h[(size_t)j*HH + idxJ[((TT)-1)*128 + ii]] * dvec_[ii]; \
                float h = 1.f / (1.f + __expf(-zv));                            \
                float dd = h - zz.y;                                            \
                if (useDarr) darr[sd4C + jj] = dd;                              \
                else { db[(TT) & 1][jj] = dd;                                   \
                       Hm[(size_t)(TT)*HH + j] = h; }                           \
            }                                                                   \
            __syncthreads();                                                    \
        }                                                                       \
    } while (0)

    // body for step TT: prefetch TT+2 into PFB, compute TT from CWB
#define BODY(TT, PFB, ZPFB, CWB, ZCW) do {                                      \
        int n4p_; bool fp_;                                                     \
        PF(cjN, cj2, wb2, PFB, ZPFB, (TT) + 2, n4p_, fp_);                      \
        int4 rn3_ = rec[(TT) + 3];                                              \
        COMPUTE((TT), CWB, ZCW);                                                \
        ciP = cjC; sd4P = sd4C;                                                 \
        cjC = cjN; sd4C = sd4N; n4C = n4N; fastC = fastN;                       \
        cjN = cj2; sd4N = sd42; n4N = n4p_; fastN = fp_;                        \
        cj2 = rfl(rn3_.x); wb2 = rfl(rn3_.y); sd42 = rfl(rn3_.z);               \
    } while (0)

    // ---- prime: prefetch steps 1 (->W1) and 2 (->W2) ----
    ciP  = rfl(rec[0].x);
    sd4P = rfl(rec[0].z);
    {
        int cj1 = rfl(rec[1].x), wb1 = rfl(rec[1].y);
        cjC = cj1; sd4C = rfl(rec[1].z);
        PF(ciP, cj1, wb1, W1, z1, 1, n4C, fastC);
        int cjB = rfl(rec[2].x), wbB = rfl(rec[2].y);
        cjN = cjB; sd4N = rfl(rec[2].z);
        PF(cjC, cjB, wbB, W2, z2, 2, n4N, fastN);
        cj2 = rfl(rec[3].x); wb2 = rfl(rec[3].y); sd42 = rfl(rec[3].z);
    }

    for (int t = 1; t <= 510; t += 3) {      // 510 = 3 * 170, exact
        BODY(t,     W0, z0, W1, z1);         // compute t   from W1, prefetch t+2 -> W0
        BODY(t + 1, W1, z1, W2, z2);         // compute t+1 from W2, prefetch t+3 -> W1
        BODY(t + 2, W2, z2, W0, z0);         // compute t+2 from W0, prefetch t+4 -> W2
    }

    // dump delta history for the parallel scatter kernel
    if (useDarr) {
        for (int i = tid * 4; i < total; i += 1024)
            *(float4*)&darrg[i] = *(float4*)&darr[i];
    }
#undef PF
#undef COMPUTE
#undef BODY
}

// ---------------- parallel scatter: Hm[t, idxJ] = step + delta ----------------
__global__ __launch_bounds__(64) void scatter_kernel(
    const float2* __restrict__ zs, const int* __restrict__ idxJ,
    const int* __restrict__ cnt, const int* __restrict__ d4offs,
    const float* __restrict__ darrg, float* __restrict__ Hm)
{
    if (d4offs[511] > DARRCAP - 64) return;   // overflow mode: scan wrote Hm directly
    const int t = blockIdx.x;
    const int c = cnt[t];
    for (int jj = threadIdx.x; jj < c; jj += 64)
        Hm[(size_t)t*HH + idxJ[t*128 + jj]] = zs[(size_t)t*128 + jj].y + darrg[d4offs[t] + jj];
}

// ---------------- row softmax over V=32000, in place on d_out ----------------
__global__ __launch_bounds__(256) void softmax_kernel(float* __restrict__ out)
{
    const int row = blockIdx.x;
    const int tid = threadIdx.x;
    float* p = out + (size_t)row * VV;
    float m = -INFINITY, l = 0.f;
    for (int i = tid; i < VV; i += 256) {          // 125 iters exactly
        float x = p[i];
        if (x > m) { l = l * __expf(m - x) + 1.f; m = x; }
        else       { l += __expf(x - m); }
    }
#pragma unroll
    for (int off = 32; off >= 1; off >>= 1) {
        float m2 = __shfl_down(m, off);
        float l2 = __shfl_down(l, off);
        float M  = fmaxf(m, m2);
        l = l * __expf(m - M) + l2 * __expf(m2 - M);
        m = M;
    }
    __shared__ float sm[4], sl[4];
    const int wid = tid >> 6, lane = tid & 63;
    if (lane == 0) { sm[wid] = m; sl[wid] = l; }
    __syncthreads();
    if (tid == 0) {
        float M = sm[0], L = sl[0];
        for (int w = 1; w < 4; ++w) {
            float M2 = fmaxf(M, sm[w]);
            L = L * __expf(M - M2) + sl[w] * __expf(sm[w] - M2);
            M = M2;
        }
        sm[0] = M; sl[0] = 1.0f / L;
    }
    __syncthreads();
    const float M = sm[0], inv = sl[0];
    for (int i = tid; i < VV; i += 256) p[i] = __expf(p[i] - M) * inv;
}

// ---------------- launcher ----------------
extern "C" void kernel_launch(void* const* d_in, const int* in_sizes, int n_in,
                              void* d_out, int out_size, void* d_ws, size_t ws_size,
                              hipStream_t stream)
{
    const float* sent = (const float*)d_in[0];
    const float* W_e  = (const float*)d_in[1];
    const float* W_x  = (const float*)d_in[2];
    const float* W_h  = (const float*)d_in[3];
    const float* W_p  = (const float*)d_in[4];
    const float* b    = (const float*)d_in[5];
    float* out = (float*)d_out;
    float* ws  = (float*)d_ws;

    // workspace layout (float offsets)
    float*  emb    = ws;                      // 262144
    float*  xp     = ws + 262144;             // 262144
    float*  U      = ws + 524288;             // 262144
    float*  Hm     = ws + 786432;             // 262144
    float*  R      = ws + 1048576;            // 512
    int*    cnt    = (int*)(ws + 1049088);    // 512
    int*    idxJ   = (int*)(ws + 1049600);    // 511*128 -> 65536
    int*    offs   = (int*)(ws + 1115136);    // 512
    int*    d4offs = (int*)(ws + 1115648);    // 512
    float2* zs     = (float2*)(ws + 1116160); // 511*128 float2 -> 130816 floats
    float*  darrg  = ws + 1246976;            // 26112
    float*  wsub   = ws + 1273088;
    long avail = (long)(ws_size / 4) - 1273088;
    int wsub_cap = (avail > 8388608L) ? 8388608 : (avail > 0 ? (int)avail : 0);

    // zero the atomic-accumulated buffers (emb, xp, U)
    hipMemsetAsync(ws, 0, (size_t)786432 * sizeof(float), stream);

    rsum_kernel<<<512, 64, 0, stream>>>(W_h, R);

    // emb = sent[:511] @ W_e^T   (K=32000, split-K 8)
    gemm_nt<<<dim3(8, 8, 8), 256, 0, stream>>>(sent, W_e, emb, ROWS, VV, VV, HH, 4000, 1);
    // xp_raw = emb @ W_x^T       (K=512, split-K 4)
    gemm_nt<<<dim3(8, 8, 4), 256, 0, stream>>>(emb, W_x, xp, ROWS, HH, HH, HH, 128, 1);

    classify_kernel<<<ROWS, 512, 0, stream>>>(xp, b, R, Hm, idxJ, cnt);

    // U = S @ W_h^T  (S currently stored in Hm)
    gemm_nt<<<dim3(8, 8, 4), 256, 0, stream>>>(Hm, W_h, U, ROWS, HH, HH, HH, 128, 1);

    prefix_kernel<<<1, 512, 0, stream>>>(cnt, offs, d4offs);
    gather_kernel<<<ROWS, 256, 0, stream>>>(W_h, xp, U, idxJ, cnt, offs, wsub, wsub_cap, zs);
    scan_kernel<<<1, 256, 0, stream>>>(zs, idxJ, cnt, offs, d4offs, wsub, wsub_cap, W_h, Hm, darrg);
    scatter_kernel<<<ROWS, 64, 0, stream>>>(zs, idxJ, cnt, d4offs, darrg, Hm);

    // logits = H @ W_p^T  -> d_out
    gemm_nt<<<dim3(500, 8, 1), 256, 0, stream>>>(Hm, W_p, out, ROWS, HH, HH, VV, 512, 0);
    softmax_kernel<<<ROWS, 256, 0, stream>>>(out);
}